// Round 1
// baseline (170.220 us; speedup 1.0000x reference)
//
#include <hip/hip_runtime.h>
#include <hip/hip_bf16.h>

#define NN 4096
#define KD 256
#define NH 8
#define DD 64
#define HD 512   // NH*DD
#define SLOPE 0.2f

// ---------------- GEMM: Wx[i][o] = sum_k x[i][k] * W[o][k] ----------------
__global__ __launch_bounds__(256) void gemm_wx(const float* __restrict__ x,
                                               const float* __restrict__ W,
                                               float* __restrict__ Wx) {
    const int bn = blockIdx.x * 64;   // output col block (o)
    const int bm = blockIdx.y * 64;   // output row block (i)
    __shared__ float As[16][68];
    __shared__ float Bs[16][68];
    const int tid = threadIdx.x;
    const int tx = tid & 15, ty = tid >> 4;
    const int lr = tid >> 2;          // 0..63 row within tile
    const int lk = (tid & 3) * 4;     // k offset 0,4,8,12
    float acc[4][4] = {};
    for (int k0 = 0; k0 < KD; k0 += 16) {
        float4 av = *(const float4*)&x[(bm + lr) * KD + k0 + lk];
        float4 bv = *(const float4*)&W[(bn + lr) * KD + k0 + lk];
        __syncthreads();
        As[lk + 0][lr] = av.x; As[lk + 1][lr] = av.y;
        As[lk + 2][lr] = av.z; As[lk + 3][lr] = av.w;
        Bs[lk + 0][lr] = bv.x; Bs[lk + 1][lr] = bv.y;
        Bs[lk + 2][lr] = bv.z; Bs[lk + 3][lr] = bv.w;
        __syncthreads();
#pragma unroll
        for (int kk = 0; kk < 16; ++kk) {
            float a0 = As[kk][ty * 4 + 0], a1 = As[kk][ty * 4 + 1];
            float a2 = As[kk][ty * 4 + 2], a3 = As[kk][ty * 4 + 3];
            float b0 = Bs[kk][tx * 4 + 0], b1 = Bs[kk][tx * 4 + 1];
            float b2 = Bs[kk][tx * 4 + 2], b3 = Bs[kk][tx * 4 + 3];
            acc[0][0] += a0 * b0; acc[0][1] += a0 * b1; acc[0][2] += a0 * b2; acc[0][3] += a0 * b3;
            acc[1][0] += a1 * b0; acc[1][1] += a1 * b1; acc[1][2] += a1 * b2; acc[1][3] += a1 * b3;
            acc[2][0] += a2 * b0; acc[2][1] += a2 * b1; acc[2][2] += a2 * b2; acc[2][3] += a2 * b3;
            acc[3][0] += a3 * b0; acc[3][1] += a3 * b1; acc[3][2] += a3 * b2; acc[3][3] += a3 * b3;
        }
    }
#pragma unroll
    for (int m = 0; m < 4; ++m)
#pragma unroll
        for (int n = 0; n < 4; ++n)
            Wx[(bm + ty * 4 + m) * HD + bn + tx * 4 + n] = acc[m][n];
}

// ---------------- s,t: per (i,h) dot of Wx row-slice with attn vecs --------
__global__ __launch_bounds__(512) void st_kernel(const float* __restrict__ Wx,
                                                 const float* __restrict__ attn,
                                                 float* __restrict__ sH,
                                                 float* __restrict__ tH) {
    const int i = blockIdx.x;
    const int tid = threadIdx.x;
    const int h = tid >> 6, d = tid & 63;
    float w = Wx[i * HD + h * DD + d];
    float sv = w * attn[h * 128 + d];
    float tv = w * attn[h * 128 + 64 + d];
#pragma unroll
    for (int off = 32; off > 0; off >>= 1) {
        sv += __shfl_down(sv, off, 64);
        tv += __shfl_down(tv, off, 64);
    }
    if (d == 0) { sH[h * NN + i] = sv; tH[h * NN + i] = tv; }
}

// ---------------- rank (brute-force sort) + scatter sorted arrays ----------
__global__ __launch_bounds__(256) void rank_kernel(const float* __restrict__ tH,
                                                   float* __restrict__ tsorted,
                                                   int* __restrict__ sortedIdx,
                                                   float* __restrict__ expT,
                                                   float* __restrict__ expT2) {
    const int h = blockIdx.y;
    const int j = blockIdx.x * 256 + threadIdx.x;
    __shared__ float tl[NN];
    for (int p = threadIdx.x; p < NN; p += 256) tl[p] = tH[h * NN + p];
    __syncthreads();
    const float myT = tl[j];
    int cnt = 0;
#pragma unroll 8
    for (int p = 0; p < NN; ++p) {
        float v = tl[p];
        cnt += (v < myT) | ((v == myT) & (p < j));
    }
    tsorted[h * NN + cnt]   = myT;
    sortedIdx[h * NN + cnt] = j;
    expT[h * NN + cnt]      = expf(myT);
    expT2[h * NN + cnt]     = expf(SLOPE * myT);
}

// ---------------- per-chunk (64) weighted sums of Wx in sorted order -------
__global__ __launch_bounds__(64) void chunk_sums(const float* __restrict__ Wx,
                                                 const int* __restrict__ sortedIdx,
                                                 const float* __restrict__ expT,
                                                 const float* __restrict__ expT2,
                                                 float* __restrict__ chunkW,
                                                 float* __restrict__ chunkW2) {
    const int c = blockIdx.x, h = blockIdx.y, d = threadIdx.x;
    float sw = 0.f, sw2 = 0.f;
    const int base = h * NN + c * 64;
    for (int k = 0; k < 64; ++k) {
        int j = sortedIdx[base + k];
        float w = expT[base + k], w2 = expT2[base + k];
        float v = Wx[j * HD + h * DD + d];
        sw += w * v; sw2 += w2 * v;
    }
    chunkW [(h * 64 + c) * 64 + d] = sw;
    chunkW2[(h * 64 + c) * 64 + d] = sw2;
}

// ---------------- exclusive scan of chunk sums (in place) + Z prefixes -----
__global__ __launch_bounds__(128) void scan_kernel(float* __restrict__ chunkW,
                                                   float* __restrict__ chunkW2,
                                                   const float* __restrict__ expT,
                                                   const float* __restrict__ expT2,
                                                   float* __restrict__ prefW,
                                                   float* __restrict__ prefW2,
                                                   float* __restrict__ prefZ,
                                                   float* __restrict__ prefZ2) {
    const int h = blockIdx.x;
    const int tid = threadIdx.x;
    __shared__ float zs[64], zs2[64];
    if (tid < 64) {
        const int d = tid;
        float acc = 0.f;
        for (int c = 0; c < 64; ++c) {
            int idx = (h * 64 + c) * 64 + d;
            float t = chunkW[idx]; chunkW[idx] = acc; acc += t;
        }
        prefW[(h * 4097 + 4096) * 64 + d] = acc;
        float a = 0.f; const int base = h * NN + d * 64;
        for (int k = 0; k < 64; ++k) a += expT[base + k];
        zs[d] = a;
    } else {
        const int d = tid - 64;
        float acc = 0.f;
        for (int c = 0; c < 64; ++c) {
            int idx = (h * 64 + c) * 64 + d;
            float t = chunkW2[idx]; chunkW2[idx] = acc; acc += t;
        }
        prefW2[(h * 4097 + 4096) * 64 + d] = acc;
        float a = 0.f; const int base = h * NN + d * 64;
        for (int k = 0; k < 64; ++k) a += expT2[base + k];
        zs2[d] = a;
    }
    __syncthreads();
    if (tid == 0) {
        float acc = 0.f;
        for (int c = 0; c < 64; ++c) { float t = zs[c]; zs[c] = acc; acc += t; }
        prefZ[h * 4097 + 4096] = acc;
    } else if (tid == 64) {
        float acc = 0.f;
        for (int c = 0; c < 64; ++c) { float t = zs2[c]; zs2[c] = acc; acc += t; }
        prefZ2[h * 4097 + 4096] = acc;
    }
    __syncthreads();
    if (tid < 64) {
        float acc = zs[tid]; const int base = h * NN + tid * 64;
        for (int k = 0; k < 64; ++k) { prefZ[h * 4097 + tid * 64 + k] = acc; acc += expT[base + k]; }
    } else {
        const int d = tid - 64;
        float acc = zs2[d]; const int base = h * NN + d * 64;
        for (int k = 0; k < 64; ++k) { prefZ2[h * 4097 + d * 64 + k] = acc; acc += expT2[base + k]; }
    }
}

// ---------------- element-granular weighted prefix sums --------------------
__global__ __launch_bounds__(64) void prefix_write(const float* __restrict__ Wx,
                                                   const int* __restrict__ sortedIdx,
                                                   const float* __restrict__ expT,
                                                   const float* __restrict__ expT2,
                                                   const float* __restrict__ chunkW,
                                                   const float* __restrict__ chunkW2,
                                                   float* __restrict__ prefW,
                                                   float* __restrict__ prefW2) {
    const int c = blockIdx.x, h = blockIdx.y, d = threadIdx.x;
    float accW  = chunkW [(h * 64 + c) * 64 + d];
    float accW2 = chunkW2[(h * 64 + c) * 64 + d];
    const int base = h * NN + c * 64;
    for (int k = 0; k < 64; ++k) {
        int p = c * 64 + k;
        prefW [(h * 4097 + p) * 64 + d] = accW;
        prefW2[(h * 4097 + p) * 64 + d] = accW2;
        int j = sortedIdx[base + k];
        float w = expT[base + k], w2 = expT2[base + k];
        float v = Wx[j * HD + h * DD + d];
        accW += w * v; accW2 += w2 * v;
    }
}

// ---------------- output: binary search + prefix lookups -------------------
__global__ __launch_bounds__(64) void out_kernel(const float* __restrict__ sH,
                                                 const float* __restrict__ tsorted,
                                                 const float* __restrict__ prefW,
                                                 const float* __restrict__ prefW2,
                                                 const float* __restrict__ prefZ,
                                                 const float* __restrict__ prefZ2,
                                                 float* __restrict__ out) {
    const int i = blockIdx.x, h = blockIdx.y, d = threadIdx.x;
    const float sv = sH[h * NN + i];
    const float negs = -sv;
    const float* ts = &tsorted[h * NN];
    int lo = 0, hi = NN;
    while (lo < hi) {
        int mid = (lo + hi) >> 1;
        if (ts[mid] <= negs) lo = mid + 1; else hi = mid;
    }
    const int c = lo;   // count of j with t_j <= -s  (negative branch)
    const float es  = expf(sv);
    const float es2 = expf(SLOPE * sv);
    const int baseT = (h * 4097 + 4096) * 64 + d;
    const int baseC = (h * 4097 + c) * 64 + d;
    float wpos = prefW[baseT] - prefW[baseC];
    float wneg = prefW2[baseC];
    float zp = prefZ[h * 4097 + 4096] - prefZ[h * 4097 + c];
    float zn = prefZ2[h * 4097 + c];
    float denom = es * zp + es2 * zn;
    out[i * HD + h * DD + d] = (es * wpos + es2 * wneg) / denom;
}

extern "C" void kernel_launch(void* const* d_in, const int* in_sizes, int n_in,
                              void* d_out, int out_size, void* d_ws, size_t ws_size,
                              hipStream_t stream) {
    const float* x    = (const float*)d_in[0];
    const float* W    = (const float*)d_in[1];
    const float* attn = (const float*)d_in[2];
    float* out = (float*)d_out;

    float* ws = (float*)d_ws;
    size_t o = 0;
    float* Wx      = ws + o; o += (size_t)NN * HD;        // 2,097,152
    float* sH      = ws + o; o += (size_t)NH * NN;        // 32768
    float* tH      = ws + o; o += (size_t)NH * NN;
    float* tsorted = ws + o; o += (size_t)NH * NN;
    float* expT    = ws + o; o += (size_t)NH * NN;
    float* expT2   = ws + o; o += (size_t)NH * NN;
    int*   sortedIdx = (int*)(ws + o); o += (size_t)NH * NN;
    float* chunkW  = ws + o; o += (size_t)NH * 64 * 64;
    float* chunkW2 = ws + o; o += (size_t)NH * 64 * 64;
    float* prefZ   = ws + o; o += 33024;                  // >= 8*4097
    float* prefZ2  = ws + o; o += 33024;
    float* prefW   = ws + o; o += (size_t)NH * 4097 * 64; // 2,097,664
    float* prefW2  = ws + o; o += (size_t)NH * 4097 * 64;

    gemm_wx<<<dim3(HD / 64, NN / 64), dim3(256), 0, stream>>>(x, W, Wx);
    st_kernel<<<dim3(NN), dim3(512), 0, stream>>>(Wx, attn, sH, tH);
    rank_kernel<<<dim3(NN / 256, NH), dim3(256), 0, stream>>>(tH, tsorted, sortedIdx, expT, expT2);
    chunk_sums<<<dim3(64, NH), dim3(64), 0, stream>>>(Wx, sortedIdx, expT, expT2, chunkW, chunkW2);
    scan_kernel<<<dim3(NH), dim3(128), 0, stream>>>(chunkW, chunkW2, expT, expT2, prefW, prefW2, prefZ, prefZ2);
    prefix_write<<<dim3(64, NH), dim3(64), 0, stream>>>(Wx, sortedIdx, expT, expT2, chunkW, chunkW2, prefW, prefW2);
    out_kernel<<<dim3(NN, NH), dim3(64), 0, stream>>>(sH, tsorted, prefW, prefW2, prefZ, prefZ2, out);
}

// Round 2
// 93.826 us; speedup vs baseline: 1.8142x; 1.8142x over previous
//
#include <hip/hip_runtime.h>
#include <hip/hip_bf16.h>

#define NN 4096
#define KD 256
#define NH 8
#define DD 64
#define HD 512   // NH*DD
#define SLOPE 0.2f
#define NSLICE 16
#define SLEN 256  // NN/NSLICE

// ---------------- GEMM: Wx[i][o] = sum_k x[i][k] * W[o][k] ----------------
__global__ __launch_bounds__(256) void gemm_wx(const float* __restrict__ x,
                                               const float* __restrict__ W,
                                               float* __restrict__ Wx) {
    const int bn = blockIdx.x * 64;   // output col block (o)
    const int bm = blockIdx.y * 64;   // output row block (i)
    __shared__ float As[16][68];
    __shared__ float Bs[16][68];
    const int tid = threadIdx.x;
    const int tx = tid & 15, ty = tid >> 4;
    const int lr = tid >> 2;          // 0..63 row within tile
    const int lk = (tid & 3) * 4;     // k offset 0,4,8,12
    float acc[4][4] = {};
    for (int k0 = 0; k0 < KD; k0 += 16) {
        float4 av = *(const float4*)&x[(bm + lr) * KD + k0 + lk];
        float4 bv = *(const float4*)&W[(bn + lr) * KD + k0 + lk];
        __syncthreads();
        As[lk + 0][lr] = av.x; As[lk + 1][lr] = av.y;
        As[lk + 2][lr] = av.z; As[lk + 3][lr] = av.w;
        Bs[lk + 0][lr] = bv.x; Bs[lk + 1][lr] = bv.y;
        Bs[lk + 2][lr] = bv.z; Bs[lk + 3][lr] = bv.w;
        __syncthreads();
#pragma unroll
        for (int kk = 0; kk < 16; ++kk) {
            float a0 = As[kk][ty * 4 + 0], a1 = As[kk][ty * 4 + 1];
            float a2 = As[kk][ty * 4 + 2], a3 = As[kk][ty * 4 + 3];
            float b0 = Bs[kk][tx * 4 + 0], b1 = Bs[kk][tx * 4 + 1];
            float b2 = Bs[kk][tx * 4 + 2], b3 = Bs[kk][tx * 4 + 3];
            acc[0][0] += a0 * b0; acc[0][1] += a0 * b1; acc[0][2] += a0 * b2; acc[0][3] += a0 * b3;
            acc[1][0] += a1 * b0; acc[1][1] += a1 * b1; acc[1][2] += a1 * b2; acc[1][3] += a1 * b3;
            acc[2][0] += a2 * b0; acc[2][1] += a2 * b1; acc[2][2] += a2 * b2; acc[2][3] += a2 * b3;
            acc[3][0] += a3 * b0; acc[3][1] += a3 * b1; acc[3][2] += a3 * b2; acc[3][3] += a3 * b3;
        }
    }
#pragma unroll
    for (int m = 0; m < 4; ++m)
#pragma unroll
        for (int n = 0; n < 4; ++n)
            Wx[(bm + ty * 4 + m) * HD + bn + tx * 4 + n] = acc[m][n];
}

// ---------------- s,t: per (i,h) dot of Wx row-slice with attn vecs --------
__global__ __launch_bounds__(512) void st_kernel(const float* __restrict__ Wx,
                                                 const float* __restrict__ attn,
                                                 float* __restrict__ sH,
                                                 float* __restrict__ tH) {
    const int i = blockIdx.x;
    const int tid = threadIdx.x;
    const int h = tid >> 6, d = tid & 63;
    float w = Wx[i * HD + h * DD + d];
    float sv = w * attn[h * 128 + d];
    float tv = w * attn[h * 128 + 64 + d];
#pragma unroll
    for (int off = 32; off > 0; off >>= 1) {
        sv += __shfl_down(sv, off, 64);
        tv += __shfl_down(tv, off, 64);
    }
    if (d == 0) { sH[h * NN + i] = sv; tH[h * NN + i] = tv; }
}

// ---------------- partial rank counts over p-slices ------------------------
__global__ __launch_bounds__(256) void count_partial(const float* __restrict__ tH,
                                                     int* __restrict__ partial) {
    const int h = blockIdx.y;
    const int slice = blockIdx.z;
    const int j = blockIdx.x * 256 + threadIdx.x;
    __shared__ float tl[SLEN];
    tl[threadIdx.x] = tH[h * NN + slice * SLEN + threadIdx.x];
    __syncthreads();
    const float myT = tH[h * NN + j];
    const int pbase = slice * SLEN;
    int cnt = 0;
#pragma unroll 8
    for (int p = 0; p < SLEN; ++p) {
        float v = tl[p];
        cnt += (v < myT) | ((v == myT) & ((pbase + p) < j));
    }
    partial[(h * NSLICE + slice) * NN + j] = cnt;
}

// ---------------- combine partial counts + scatter sorted arrays -----------
__global__ __launch_bounds__(256) void scatter_kernel(const float* __restrict__ tH,
                                                      const int* __restrict__ partial,
                                                      float* __restrict__ tsorted,
                                                      int* __restrict__ sortedIdx,
                                                      float* __restrict__ expT,
                                                      float* __restrict__ expT2) {
    const int h = blockIdx.y;
    const int j = blockIdx.x * 256 + threadIdx.x;
    int r = 0;
#pragma unroll
    for (int s = 0; s < NSLICE; ++s) r += partial[(h * NSLICE + s) * NN + j];
    const float myT = tH[h * NN + j];
    tsorted[h * NN + r]   = myT;
    sortedIdx[h * NN + r] = j;
    expT[h * NN + r]      = expf(myT);
    expT2[h * NN + r]     = expf(SLOPE * myT);
}

// ---------------- per-chunk (64) weighted sums of Wx in sorted order -------
__global__ __launch_bounds__(256) void chunk_sums(const float* __restrict__ Wx,
                                                  const int* __restrict__ sortedIdx,
                                                  const float* __restrict__ expT,
                                                  const float* __restrict__ expT2,
                                                  float* __restrict__ chunkW,
                                                  float* __restrict__ chunkW2) {
    const int c = blockIdx.x, h = blockIdx.y;
    const int wid = threadIdx.x >> 6, d = threadIdx.x & 63;
    __shared__ float red[4][64], red2[4][64];
    float sw = 0.f, sw2 = 0.f;
    const int base = h * NN + c * 64;
#pragma unroll
    for (int kk = 0; kk < 16; ++kk) {
        int k = wid * 16 + kk;
        int j = sortedIdx[base + k];
        float v = Wx[j * HD + h * DD + d];
        sw  += expT[base + k]  * v;
        sw2 += expT2[base + k] * v;
    }
    red[wid][d] = sw; red2[wid][d] = sw2;
    __syncthreads();
    if (wid == 0) {
        float a  = red[0][d]  + red[1][d]  + red[2][d]  + red[3][d];
        float a2 = red2[0][d] + red2[1][d] + red2[2][d] + red2[3][d];
        chunkW [(h * 64 + c) * 64 + d] = a;
        chunkW2[(h * 64 + c) * 64 + d] = a2;
    }
}

// ---------------- chunk-level scans (LDS-staged) + Z element scans ---------
__global__ __launch_bounds__(256) void scan_kernel(float* __restrict__ chunkW,
                                                   float* __restrict__ chunkW2,
                                                   const float* __restrict__ expT,
                                                   const float* __restrict__ expT2,
                                                   float* __restrict__ prefW,
                                                   float* __restrict__ prefW2,
                                                   float* __restrict__ prefZ,
                                                   float* __restrict__ prefZ2) {
    const int h = blockIdx.x;
    const int tid = threadIdx.x;
    __shared__ float cw[64 * 64];
    __shared__ float cw2[64 * 64];
    __shared__ float ss[257];
#pragma unroll
    for (int it = 0; it < 16; ++it) {
        int lin = it * 256 + tid;
        cw[lin]  = chunkW [h * 4096 + lin];
        cw2[lin] = chunkW2[h * 4096 + lin];
    }
    __syncthreads();
    if (tid < 64) {
        float acc = 0.f;
        for (int c = 0; c < 64; ++c) { float t = cw[c * 64 + tid]; cw[c * 64 + tid] = acc; acc += t; }
        prefW[(h * 4097 + 4096) * 64 + tid] = acc;
    } else if (tid < 128) {
        int d = tid - 64; float acc = 0.f;
        for (int c = 0; c < 64; ++c) { float t = cw2[c * 64 + d]; cw2[c * 64 + d] = acc; acc += t; }
        prefW2[(h * 4097 + 4096) * 64 + d] = acc;
    }
    __syncthreads();
#pragma unroll
    for (int it = 0; it < 16; ++it) {
        int lin = it * 256 + tid;
        chunkW [h * 4096 + lin] = cw[lin];
        chunkW2[h * 4096 + lin] = cw2[lin];
    }
    // ---- Z scan for expT ----
    {
        float vals[16]; float seg = 0.f;
        const int b = h * NN + tid * 16;
#pragma unroll
        for (int e = 0; e < 16; ++e) { vals[e] = expT[b + e]; seg += vals[e]; }
        ss[tid] = seg;
        __syncthreads();
        if (tid == 0) {
            float acc = 0.f;
            for (int q = 0; q < 256; ++q) { float t = ss[q]; ss[q] = acc; acc += t; }
            ss[256] = acc;
        }
        __syncthreads();
        float acc = ss[tid];
#pragma unroll
        for (int e = 0; e < 16; ++e) { prefZ[h * 4097 + tid * 16 + e] = acc; acc += vals[e]; }
        if (tid == 0) prefZ[h * 4097 + 4096] = ss[256];
    }
    __syncthreads();
    // ---- Z scan for expT2 ----
    {
        float vals[16]; float seg = 0.f;
        const int b = h * NN + tid * 16;
#pragma unroll
        for (int e = 0; e < 16; ++e) { vals[e] = expT2[b + e]; seg += vals[e]; }
        ss[tid] = seg;
        __syncthreads();
        if (tid == 0) {
            float acc = 0.f;
            for (int q = 0; q < 256; ++q) { float t = ss[q]; ss[q] = acc; acc += t; }
            ss[256] = acc;
        }
        __syncthreads();
        float acc = ss[tid];
#pragma unroll
        for (int e = 0; e < 16; ++e) { prefZ2[h * 4097 + tid * 16 + e] = acc; acc += vals[e]; }
        if (tid == 0) prefZ2[h * 4097 + 4096] = ss[256];
    }
}

// ---------------- element-granular weighted prefix sums --------------------
__global__ __launch_bounds__(256) void prefix_write(const float* __restrict__ Wx,
                                                    const int* __restrict__ sortedIdx,
                                                    const float* __restrict__ expT,
                                                    const float* __restrict__ expT2,
                                                    const float* __restrict__ chunkW,
                                                    const float* __restrict__ chunkW2,
                                                    float* __restrict__ prefW,
                                                    float* __restrict__ prefW2) {
    const int c = blockIdx.x, h = blockIdx.y;
    const int tid = threadIdx.x;
    const int wid = tid >> 6, d = tid & 63;
    __shared__ float val[64][64];
    __shared__ float val2[64][64];
    const int base = h * NN + c * 64;
#pragma unroll
    for (int kk = 0; kk < 16; ++kk) {
        int k = wid * 16 + kk;
        int j = sortedIdx[base + k];
        float v = Wx[j * HD + h * DD + d];
        val[k][d]  = expT[base + k]  * v;
        val2[k][d] = expT2[base + k] * v;
    }
    __syncthreads();
    if (tid < 64) {
        float acc = chunkW[(h * 64 + c) * 64 + tid];
        for (int k = 0; k < 64; ++k) { float t = val[k][tid]; val[k][tid] = acc; acc += t; }
    } else if (tid < 128) {
        int dd = tid - 64;
        float acc = chunkW2[(h * 64 + c) * 64 + dd];
        for (int k = 0; k < 64; ++k) { float t = val2[k][dd]; val2[k][dd] = acc; acc += t; }
    }
    __syncthreads();
#pragma unroll
    for (int kk = 0; kk < 16; ++kk) {
        int k = wid * 16 + kk;
        int p = c * 64 + k;
        prefW [(h * 4097 + p) * 64 + d] = val[k][d];
        prefW2[(h * 4097 + p) * 64 + d] = val2[k][d];
    }
}

// ---------------- output: binary search + prefix lookups -------------------
__global__ __launch_bounds__(256) void out_kernel(const float* __restrict__ sH,
                                                  const float* __restrict__ tsorted,
                                                  const float* __restrict__ prefW,
                                                  const float* __restrict__ prefW2,
                                                  const float* __restrict__ prefZ,
                                                  const float* __restrict__ prefZ2,
                                                  float* __restrict__ out) {
    const int h = blockIdx.y;
    const int i = blockIdx.x * 4 + (threadIdx.x >> 6);
    const int d = threadIdx.x & 63;
    const float sv = sH[h * NN + i];
    const float negs = -sv;
    const float* ts = &tsorted[h * NN];
    int lo = 0, hi = NN;
    while (lo < hi) {
        int mid = (lo + hi) >> 1;
        if (ts[mid] <= negs) lo = mid + 1; else hi = mid;
    }
    const int c = lo;   // count of j with t_j <= -s  (negative branch)
    const float es  = expf(sv);
    const float es2 = expf(SLOPE * sv);
    const int baseT = (h * 4097 + 4096) * 64 + d;
    const int baseC = (h * 4097 + c) * 64 + d;
    float wpos = prefW[baseT] - prefW[baseC];
    float wneg = prefW2[baseC];
    float zp = prefZ[h * 4097 + 4096] - prefZ[h * 4097 + c];
    float zn = prefZ2[h * 4097 + c];
    float denom = es * zp + es2 * zn;
    out[i * HD + h * DD + d] = (es * wpos + es2 * wneg) / denom;
}

extern "C" void kernel_launch(void* const* d_in, const int* in_sizes, int n_in,
                              void* d_out, int out_size, void* d_ws, size_t ws_size,
                              hipStream_t stream) {
    const float* x    = (const float*)d_in[0];
    const float* W    = (const float*)d_in[1];
    const float* attn = (const float*)d_in[2];
    float* out = (float*)d_out;

    float* ws = (float*)d_ws;
    size_t o = 0;
    float* Wx      = ws + o; o += (size_t)NN * HD;        // 2,097,152
    float* sH      = ws + o; o += (size_t)NH * NN;        // 32768
    float* tH      = ws + o; o += (size_t)NH * NN;
    float* tsorted = ws + o; o += (size_t)NH * NN;
    float* expT    = ws + o; o += (size_t)NH * NN;
    float* expT2   = ws + o; o += (size_t)NH * NN;
    int*   sortedIdx = (int*)(ws + o); o += (size_t)NH * NN;
    float* chunkW  = ws + o; o += (size_t)NH * 64 * 64;
    float* chunkW2 = ws + o; o += (size_t)NH * 64 * 64;
    float* prefZ   = ws + o; o += 33024;                  // >= 8*4097
    float* prefZ2  = ws + o; o += 33024;
    float* prefW   = ws + o; o += (size_t)NH * 4097 * 64; // 2,097,664
    float* prefW2  = ws + o; o += (size_t)NH * 4097 * 64;
    // partial counts alias prefW's space (prefW is first written later, by scan_kernel)
    int* partial = (int*)prefW;   // needs NH*NSLICE*NN = 524,288 ints

    gemm_wx<<<dim3(HD / 64, NN / 64), dim3(256), 0, stream>>>(x, W, Wx);
    st_kernel<<<dim3(NN), dim3(512), 0, stream>>>(Wx, attn, sH, tH);
    count_partial<<<dim3(NN / 256, NH, NSLICE), dim3(256), 0, stream>>>(tH, partial);
    scatter_kernel<<<dim3(NN / 256, NH), dim3(256), 0, stream>>>(tH, partial, tsorted, sortedIdx, expT, expT2);
    chunk_sums<<<dim3(64, NH), dim3(256), 0, stream>>>(Wx, sortedIdx, expT, expT2, chunkW, chunkW2);
    scan_kernel<<<dim3(NH), dim3(256), 0, stream>>>(chunkW, chunkW2, expT, expT2, prefW, prefW2, prefZ, prefZ2);
    prefix_write<<<dim3(64, NH), dim3(256), 0, stream>>>(Wx, sortedIdx, expT, expT2, chunkW, chunkW2, prefW, prefW2);
    out_kernel<<<dim3(NN / 4, NH), dim3(256), 0, stream>>>(sH, tsorted, prefW, prefW2, prefZ, prefZ2, out);
}

// Round 3
// 74.172 us; speedup vs baseline: 2.2949x; 1.2650x over previous
//
#include <hip/hip_runtime.h>
#include <hip/hip_bf16.h>

#define NN 4096
#define KD 256
#define NH 8
#define DD 64
#define HD 512   // NH*DD
#define SLOPE 0.2f
#define NSLICE 16
#define SLEN 256  // NN/NSLICE

// ---- GEMM (64x64 tiles) + fused s,t epilogue.  blockIdx.x = head. --------
__global__ __launch_bounds__(256) void gemm_st(const float* __restrict__ x,
                                               const float* __restrict__ W,
                                               const float* __restrict__ attn,
                                               float* __restrict__ Wx,
                                               float* __restrict__ sH,
                                               float* __restrict__ tH) {
    const int h  = blockIdx.x;
    const int bn = h * 64;
    const int bm = blockIdx.y * 64;
    __shared__ float As[16][68];
    __shared__ float Bs[16][68];
    const int tid = threadIdx.x;
    const int tx = tid & 15, ty = tid >> 4;
    const int lr = tid >> 2;
    const int lk = (tid & 3) * 4;
    float acc[4][4] = {};
    for (int k0 = 0; k0 < KD; k0 += 16) {
        float4 av = *(const float4*)&x[(bm + lr) * KD + k0 + lk];
        float4 bv = *(const float4*)&W[(bn + lr) * KD + k0 + lk];
        __syncthreads();
        As[lk + 0][lr] = av.x; As[lk + 1][lr] = av.y;
        As[lk + 2][lr] = av.z; As[lk + 3][lr] = av.w;
        Bs[lk + 0][lr] = bv.x; Bs[lk + 1][lr] = bv.y;
        Bs[lk + 2][lr] = bv.z; Bs[lk + 3][lr] = bv.w;
        __syncthreads();
#pragma unroll
        for (int kk = 0; kk < 16; ++kk) {
            float4 a = *(const float4*)&As[kk][ty * 4];
            float4 b = *(const float4*)&Bs[kk][tx * 4];
            acc[0][0] += a.x * b.x; acc[0][1] += a.x * b.y; acc[0][2] += a.x * b.z; acc[0][3] += a.x * b.w;
            acc[1][0] += a.y * b.x; acc[1][1] += a.y * b.y; acc[1][2] += a.y * b.z; acc[1][3] += a.y * b.w;
            acc[2][0] += a.z * b.x; acc[2][1] += a.z * b.y; acc[2][2] += a.z * b.z; acc[2][3] += a.z * b.w;
            acc[3][0] += a.w * b.x; acc[3][1] += a.w * b.y; acc[3][2] += a.w * b.z; acc[3][3] += a.w * b.w;
        }
    }
#pragma unroll
    for (int m = 0; m < 4; ++m)
#pragma unroll
        for (int n = 0; n < 4; ++n)
            Wx[(bm + ty * 4 + m) * HD + bn + tx * 4 + n] = acc[m][n];
    // fused s,t: dot 64-wide rows with attn vectors, butterfly over tx lanes
    float4 as4 = *(const float4*)&attn[h * 128 + tx * 4];
    float4 at4 = *(const float4*)&attn[h * 128 + 64 + tx * 4];
#pragma unroll
    for (int m = 0; m < 4; ++m) {
        float s = acc[m][0] * as4.x + acc[m][1] * as4.y + acc[m][2] * as4.z + acc[m][3] * as4.w;
        float t = acc[m][0] * at4.x + acc[m][1] * at4.y + acc[m][2] * at4.z + acc[m][3] * at4.w;
#pragma unroll
        for (int off = 1; off < 16; off <<= 1) {
            s += __shfl_xor(s, off, 16);
            t += __shfl_xor(t, off, 16);
        }
        if (tx == 0) {
            sH[h * NN + bm + ty * 4 + m] = s;
            tH[h * NN + bm + ty * 4 + m] = t;
        }
    }
}

// ---- partial rank counts AND partial threshold counts over p-slices ------
__global__ __launch_bounds__(256) void count_partial(const float* __restrict__ tH,
                                                     const float* __restrict__ sH,
                                                     int* __restrict__ partialR,
                                                     int* __restrict__ partialC) {
    const int h = blockIdx.y;
    const int slice = blockIdx.z;
    const int j = blockIdx.x * 256 + threadIdx.x;
    __shared__ float tl[SLEN];
    tl[threadIdx.x] = tH[h * NN + slice * SLEN + threadIdx.x];
    __syncthreads();
    const float myT  = tH[h * NN + j];
    const float negS = -sH[h * NN + j];
    const int pbase = slice * SLEN;
    int r = 0, cs = 0;
#pragma unroll 8
    for (int p = 0; p < SLEN; ++p) {
        float v = tl[p];
        r  += (v < myT) | ((v == myT) & ((pbase + p) < j));
        cs += (v <= negS);
    }
    partialR[(h * NSLICE + slice) * NN + j] = r;
    partialC[(h * NSLICE + slice) * NN + j] = cs;
}

// ---- combine partials: scatter sorted arrays + cIdx ----------------------
__global__ __launch_bounds__(256) void scatter_kernel(const float* __restrict__ tH,
                                                      const int* __restrict__ partialR,
                                                      const int* __restrict__ partialC,
                                                      int* __restrict__ sortedIdx,
                                                      float* __restrict__ expT,
                                                      float* __restrict__ expT2,
                                                      int* __restrict__ cIdx) {
    const int h = blockIdx.y;
    const int j = blockIdx.x * 256 + threadIdx.x;
    int r = 0, cs = 0;
#pragma unroll
    for (int s = 0; s < NSLICE; ++s) {
        r  += partialR[(h * NSLICE + s) * NN + j];
        cs += partialC[(h * NSLICE + s) * NN + j];
    }
    const float myT = tH[h * NN + j];
    sortedIdx[h * NN + r] = j;
    expT[h * NN + r]      = expf(myT);
    expT2[h * NN + r]     = expf(SLOPE * myT);
    cIdx[h * NN + j]      = cs;
}

// ---- gather Wx in sorted order; chunk-local exclusive prefixes in regs ---
__global__ __launch_bounds__(256) void local_prefix(const float* __restrict__ Wx,
                                                    const int* __restrict__ sortedIdx,
                                                    const float* __restrict__ expT,
                                                    const float* __restrict__ expT2,
                                                    float* __restrict__ localW,
                                                    float* __restrict__ localW2,
                                                    float* __restrict__ chunkTotW,
                                                    float* __restrict__ chunkTotW2,
                                                    float* __restrict__ localZ,
                                                    float* __restrict__ localZ2,
                                                    float* __restrict__ chunkZtot,
                                                    float* __restrict__ chunkZtot2) {
    const int c = blockIdx.x, h = blockIdx.y;
    const int tid = threadIdx.x;
    const int wid = tid >> 6, d = tid & 63;
    const int base = h * NN + c * 64;
    __shared__ float sums[4][64], sums2[4][64];
    float run = 0.f, run2 = 0.f;
    float ex[16], ex2[16];
#pragma unroll
    for (int kk = 0; kk < 16; ++kk) {
        int k = wid * 16 + kk;
        int j = sortedIdx[base + k];
        float w  = expT[base + k];
        float w2 = expT2[base + k];
        float v = Wx[j * HD + h * DD + d];
        ex[kk]  = run;  run  += w  * v;
        ex2[kk] = run2; run2 += w2 * v;
    }
    sums[wid][d] = run; sums2[wid][d] = run2;
    __syncthreads();
    float off = 0.f, off2 = 0.f;
    for (int w = 0; w < 4; ++w) {
        if (w < wid) { off += sums[w][d]; off2 += sums2[w][d]; }
    }
#pragma unroll
    for (int kk = 0; kk < 16; ++kk) {
        int k = wid * 16 + kk;
        localW [(h * NN + c * 64 + k) * 64 + d] = ex[kk]  + off;
        localW2[(h * NN + c * 64 + k) * 64 + d] = ex2[kk] + off2;
    }
    if (wid == 3) {
        chunkTotW [(h * 64 + c) * 64 + d] = off  + run;
        chunkTotW2[(h * 64 + c) * 64 + d] = off2 + run2;
    }
    // chunk-local Z scans (wave 0: expT, wave 1: expT2)
    if (wid == 0) {
        float z0 = expT[base + d];
        float z = z0;
#pragma unroll
        for (int o = 1; o < 64; o <<= 1) { float n = __shfl_up(z, o, 64); if (d >= o) z += n; }
        localZ[h * NN + c * 64 + d] = z - z0;
        if (d == 63) chunkZtot[h * 64 + c] = z;
    } else if (wid == 1) {
        float z0 = expT2[base + d];
        float z = z0;
#pragma unroll
        for (int o = 1; o < 64; o <<= 1) { float n = __shfl_up(z, o, 64); if (d >= o) z += n; }
        localZ2[h * NN + c * 64 + d] = z - z0;
        if (d == 63) chunkZtot2[h * 64 + c] = z;
    }
}

// ---- per-head scan of chunk totals (in place) + grand totals -------------
__global__ __launch_bounds__(256) void chunk_scan(float* __restrict__ chunkTotW,
                                                  float* __restrict__ chunkTotW2,
                                                  float* __restrict__ chunkZtot,
                                                  float* __restrict__ chunkZtot2,
                                                  float* __restrict__ totW,
                                                  float* __restrict__ totW2,
                                                  float* __restrict__ Ztot,
                                                  float* __restrict__ Ztot2) {
    const int h = blockIdx.x;
    const int tid = threadIdx.x;
    const int lane = tid & 63;
    __shared__ float cw[64 * 64];
    __shared__ float cw2[64 * 64];
    __shared__ float zb[64], zb2[64];
#pragma unroll
    for (int it = 0; it < 16; ++it) {
        int lin = it * 256 + tid;
        cw[lin]  = chunkTotW [h * 4096 + lin];
        cw2[lin] = chunkTotW2[h * 4096 + lin];
    }
    if (tid >= 128 && tid < 192) zb[lane]  = chunkZtot [h * 64 + lane];
    if (tid >= 192)              zb2[lane] = chunkZtot2[h * 64 + lane];
    __syncthreads();
    if (tid < 64) {
        float acc = 0.f;
        for (int c = 0; c < 64; ++c) { int idx = c * 64 + tid; float t = cw[idx]; cw[idx] = acc; acc += t; }
        totW[h * 64 + tid] = acc;
    } else if (tid < 128) {
        int d = tid - 64;
        float acc = 0.f;
        for (int c = 0; c < 64; ++c) { int idx = c * 64 + d; float t = cw2[idx]; cw2[idx] = acc; acc += t; }
        totW2[h * 64 + d] = acc;
    } else if (tid < 192) {
        float z0 = zb[lane];
        float z = z0;
#pragma unroll
        for (int o = 1; o < 64; o <<= 1) { float n = __shfl_up(z, o, 64); if (lane >= o) z += n; }
        chunkZtot[h * 64 + lane] = z - z0;
        if (lane == 63) Ztot[h] = z;
    } else {
        float z0 = zb2[lane];
        float z = z0;
#pragma unroll
        for (int o = 1; o < 64; o <<= 1) { float n = __shfl_up(z, o, 64); if (lane >= o) z += n; }
        chunkZtot2[h * 64 + lane] = z - z0;
        if (lane == 63) Ztot2[h] = z;
    }
    __syncthreads();
#pragma unroll
    for (int it = 0; it < 16; ++it) {
        int lin = it * 256 + tid;
        chunkTotW [h * 4096 + lin] = cw[lin];
        chunkTotW2[h * 4096 + lin] = cw2[lin];
    }
}

// ---- output: pure streaming lookups --------------------------------------
__global__ __launch_bounds__(256) void out_kernel(const float* __restrict__ sH,
                                                  const int* __restrict__ cIdx,
                                                  const float* __restrict__ localW,
                                                  const float* __restrict__ localW2,
                                                  const float* __restrict__ chunkTotW,
                                                  const float* __restrict__ chunkTotW2,
                                                  const float* __restrict__ localZ,
                                                  const float* __restrict__ localZ2,
                                                  const float* __restrict__ chunkZtot,
                                                  const float* __restrict__ chunkZtot2,
                                                  const float* __restrict__ totW,
                                                  const float* __restrict__ totW2,
                                                  const float* __restrict__ Ztot,
                                                  const float* __restrict__ Ztot2,
                                                  float* __restrict__ out) {
    const int h = blockIdx.y;
    const int i = blockIdx.x * 4 + (threadIdx.x >> 6);
    const int d = threadIdx.x & 63;
    const float sv = sH[h * NN + i];
    const int c = cIdx[h * NN + i];
    const float es  = expf(sv);
    const float es2 = expf(SLOPE * sv);
    float wpos, wneg, zp, zn;
    if (c == NN) {
        wpos = 0.f; zp = 0.f;
        wneg = totW2[h * 64 + d];
        zn   = Ztot2[h];
    } else {
        float pw  = localW [(h * NN + c) * 64 + d] + chunkTotW [(h * 64 + (c >> 6)) * 64 + d];
        float pw2 = localW2[(h * NN + c) * 64 + d] + chunkTotW2[(h * 64 + (c >> 6)) * 64 + d];
        wpos = totW[h * 64 + d] - pw;
        wneg = pw2;
        float pz  = localZ [h * NN + c] + chunkZtot [h * 64 + (c >> 6)];
        float pz2 = localZ2[h * NN + c] + chunkZtot2[h * 64 + (c >> 6)];
        zp = Ztot[h] - pz;
        zn = pz2;
    }
    out[i * HD + h * DD + d] = (es * wpos + es2 * wneg) / (es * zp + es2 * zn);
}

extern "C" void kernel_launch(void* const* d_in, const int* in_sizes, int n_in,
                              void* d_out, int out_size, void* d_ws, size_t ws_size,
                              hipStream_t stream) {
    const float* x    = (const float*)d_in[0];
    const float* W    = (const float*)d_in[1];
    const float* attn = (const float*)d_in[2];
    float* out = (float*)d_out;

    float* ws = (float*)d_ws;
    size_t o = 0;
    float* Wx        = ws + o; o += (size_t)NN * HD;      // 2,097,152
    float* sH        = ws + o; o += (size_t)NH * NN;
    float* tH        = ws + o; o += (size_t)NH * NN;
    float* expT      = ws + o; o += (size_t)NH * NN;
    float* expT2     = ws + o; o += (size_t)NH * NN;
    int*   sortedIdx = (int*)(ws + o); o += (size_t)NH * NN;
    int*   cIdx      = (int*)(ws + o); o += (size_t)NH * NN;
    float* localZ    = ws + o; o += (size_t)NH * NN;
    float* localZ2   = ws + o; o += (size_t)NH * NN;
    float* chunkTotW  = ws + o; o += (size_t)NH * 64 * 64;
    float* chunkTotW2 = ws + o; o += (size_t)NH * 64 * 64;
    float* chunkZtot  = ws + o; o += (size_t)NH * 64;
    float* chunkZtot2 = ws + o; o += (size_t)NH * 64;
    float* totW   = ws + o; o += (size_t)NH * 64;
    float* totW2  = ws + o; o += (size_t)NH * 64;
    float* Ztot   = ws + o; o += 64;
    float* Ztot2  = ws + o; o += 64;
    float* localW  = ws + o; o += (size_t)NH * NN * 64;   // 2,097,152
    float* localW2 = ws + o; o += (size_t)NH * NN * 64;
    // partial count arrays alias localW/localW2 (consumed before those are written)
    int* partialR = (int*)localW;    // NH*NSLICE*NN = 524,288 ints
    int* partialC = (int*)localW2;

    gemm_st<<<dim3(NH, NN / 64), dim3(256), 0, stream>>>(x, W, attn, Wx, sH, tH);
    count_partial<<<dim3(NN / 256, NH, NSLICE), dim3(256), 0, stream>>>(tH, sH, partialR, partialC);
    scatter_kernel<<<dim3(NN / 256, NH), dim3(256), 0, stream>>>(tH, partialR, partialC, sortedIdx, expT, expT2, cIdx);
    local_prefix<<<dim3(64, NH), dim3(256), 0, stream>>>(Wx, sortedIdx, expT, expT2, localW, localW2,
                                                         chunkTotW, chunkTotW2, localZ, localZ2, chunkZtot, chunkZtot2);
    chunk_scan<<<dim3(NH), dim3(256), 0, stream>>>(chunkTotW, chunkTotW2, chunkZtot, chunkZtot2,
                                                   totW, totW2, Ztot, Ztot2);
    out_kernel<<<dim3(NN / 4, NH), dim3(256), 0, stream>>>(sH, cIdx, localW, localW2, chunkTotW, chunkTotW2,
                                                           localZ, localZ2, chunkZtot, chunkZtot2,
                                                           totW, totW2, Ztot, Ztot2, out);
}

// Round 4
// 72.967 us; speedup vs baseline: 2.3328x; 1.0165x over previous
//
#include <hip/hip_runtime.h>
#include <hip/hip_bf16.h>

#define NN 4096
#define KD 256
#define NH 8
#define DD 64
#define HD 512   // NH*DD
#define SLOPE 0.2f
#define NSLICE 8
#define SLEN 512  // NN/NSLICE

// ---- GEMM (64x64 tiles, BK=32) + fused s,t epilogue.  blockIdx.x = head. --
__global__ __launch_bounds__(256) void gemm_st(const float* __restrict__ x,
                                               const float* __restrict__ W,
                                               const float* __restrict__ attn,
                                               float* __restrict__ Wx,
                                               float* __restrict__ sH,
                                               float* __restrict__ tH) {
    const int h  = blockIdx.x;
    const int bn = h * 64;
    const int bm = blockIdx.y * 64;
    __shared__ float As[32][68];
    __shared__ float Bs[32][68];
    const int tid = threadIdx.x;
    const int tx = tid & 15, ty = tid >> 4;
    const int srow = tid >> 2;          // 0..63
    const int skq  = (tid & 3) * 8;     // 0,8,16,24
    float acc[4][4] = {};
    for (int k0 = 0; k0 < KD; k0 += 32) {
        float4 a0 = *(const float4*)&x[(bm + srow) * KD + k0 + skq];
        float4 a1 = *(const float4*)&x[(bm + srow) * KD + k0 + skq + 4];
        float4 b0 = *(const float4*)&W[(bn + srow) * KD + k0 + skq];
        float4 b1 = *(const float4*)&W[(bn + srow) * KD + k0 + skq + 4];
        __syncthreads();
        As[skq + 0][srow] = a0.x; As[skq + 1][srow] = a0.y;
        As[skq + 2][srow] = a0.z; As[skq + 3][srow] = a0.w;
        As[skq + 4][srow] = a1.x; As[skq + 5][srow] = a1.y;
        As[skq + 6][srow] = a1.z; As[skq + 7][srow] = a1.w;
        Bs[skq + 0][srow] = b0.x; Bs[skq + 1][srow] = b0.y;
        Bs[skq + 2][srow] = b0.z; Bs[skq + 3][srow] = b0.w;
        Bs[skq + 4][srow] = b1.x; Bs[skq + 5][srow] = b1.y;
        Bs[skq + 6][srow] = b1.z; Bs[skq + 7][srow] = b1.w;
        __syncthreads();
#pragma unroll
        for (int kk = 0; kk < 32; ++kk) {
            float4 a = *(const float4*)&As[kk][ty * 4];
            float4 b = *(const float4*)&Bs[kk][tx * 4];
            acc[0][0] += a.x * b.x; acc[0][1] += a.x * b.y; acc[0][2] += a.x * b.z; acc[0][3] += a.x * b.w;
            acc[1][0] += a.y * b.x; acc[1][1] += a.y * b.y; acc[1][2] += a.y * b.z; acc[1][3] += a.y * b.w;
            acc[2][0] += a.z * b.x; acc[2][1] += a.z * b.y; acc[2][2] += a.z * b.z; acc[2][3] += a.z * b.w;
            acc[3][0] += a.w * b.x; acc[3][1] += a.w * b.y; acc[3][2] += a.w * b.z; acc[3][3] += a.w * b.w;
        }
    }
#pragma unroll
    for (int m = 0; m < 4; ++m)
        *(float4*)&Wx[(bm + ty * 4 + m) * HD + bn + tx * 4] = *(const float4*)&acc[m][0];
    // fused s,t: dot 64-wide rows with attn vectors, butterfly over tx lanes
    float4 as4 = *(const float4*)&attn[h * 128 + tx * 4];
    float4 at4 = *(const float4*)&attn[h * 128 + 64 + tx * 4];
#pragma unroll
    for (int m = 0; m < 4; ++m) {
        float s = acc[m][0] * as4.x + acc[m][1] * as4.y + acc[m][2] * as4.z + acc[m][3] * as4.w;
        float t = acc[m][0] * at4.x + acc[m][1] * at4.y + acc[m][2] * at4.z + acc[m][3] * at4.w;
#pragma unroll
        for (int off = 1; off < 16; off <<= 1) {
            s += __shfl_xor(s, off, 16);
            t += __shfl_xor(t, off, 16);
        }
        if (tx == 0) {
            sH[h * NN + bm + ty * 4 + m] = s;
            tH[h * NN + bm + ty * 4 + m] = t;
        }
    }
}

// ---- partial rank + threshold counts; off-diagonal slices use 1-cmp form --
__global__ __launch_bounds__(256) void count_partial(const float* __restrict__ tH,
                                                     const float* __restrict__ sH,
                                                     unsigned short* __restrict__ partialR,
                                                     unsigned short* __restrict__ partialC) {
    const int h = blockIdx.y;
    const int slice = blockIdx.z;
    const int jb = blockIdx.x;
    const int j = jb * 256 + threadIdx.x;
    __shared__ float tl[SLEN];
    for (int p = threadIdx.x; p < SLEN; p += 256) tl[p] = tH[h * NN + slice * SLEN + p];
    __syncthreads();
    const float myT  = tH[h * NN + j];
    const float negS = -sH[h * NN + j];
    const float4* tl4 = (const float4*)tl;
    int r = 0, cs = 0;
    if (slice == (jb >> 1)) {            // mixed slice: exact tie-break
        const int pbase = slice * SLEN;
#pragma unroll 4
        for (int p4 = 0; p4 < SLEN / 4; ++p4) {
            float4 v = tl4[p4];
            int p = pbase + p4 * 4;
            r += (v.x < myT) | ((v.x == myT) & ((p + 0) < j));
            r += (v.y < myT) | ((v.y == myT) & ((p + 1) < j));
            r += (v.z < myT) | ((v.z == myT) & ((p + 2) < j));
            r += (v.w < myT) | ((v.w == myT) & ((p + 3) < j));
            cs += (v.x <= negS) + (v.y <= negS) + (v.z <= negS) + (v.w <= negS);
        }
    } else if (slice < (jb >> 1)) {      // all p < j: tie counts
#pragma unroll 4
        for (int p4 = 0; p4 < SLEN / 4; ++p4) {
            float4 v = tl4[p4];
            r  += (v.x <= myT) + (v.y <= myT) + (v.z <= myT) + (v.w <= myT);
            cs += (v.x <= negS) + (v.y <= negS) + (v.z <= negS) + (v.w <= negS);
        }
    } else {                              // all p > j: tie doesn't count
#pragma unroll 4
        for (int p4 = 0; p4 < SLEN / 4; ++p4) {
            float4 v = tl4[p4];
            r  += (v.x < myT) + (v.y < myT) + (v.z < myT) + (v.w < myT);
            cs += (v.x <= negS) + (v.y <= negS) + (v.z <= negS) + (v.w <= negS);
        }
    }
    partialR[(h * NSLICE + slice) * NN + j] = (unsigned short)r;
    partialC[(h * NSLICE + slice) * NN + j] = (unsigned short)cs;
}

// ---- combine partials: scatter sorted arrays + cIdx ----------------------
__global__ __launch_bounds__(256) void scatter_kernel(const float* __restrict__ tH,
                                                      const unsigned short* __restrict__ partialR,
                                                      const unsigned short* __restrict__ partialC,
                                                      int* __restrict__ sortedIdx,
                                                      float* __restrict__ expT,
                                                      float* __restrict__ expT2,
                                                      int* __restrict__ cIdx) {
    const int h = blockIdx.y;
    const int j = blockIdx.x * 256 + threadIdx.x;
    int r = 0, cs = 0;
#pragma unroll
    for (int s = 0; s < NSLICE; ++s) {
        r  += partialR[(h * NSLICE + s) * NN + j];
        cs += partialC[(h * NSLICE + s) * NN + j];
    }
    const float myT = tH[h * NN + j];
    sortedIdx[h * NN + r] = j;
    expT[h * NN + r]      = expf(myT);
    expT2[h * NN + r]     = expf(SLOPE * myT);
    cIdx[h * NN + j]      = cs;
}

// ---- gather Wx in sorted order; chunk-local exclusive prefixes in regs ---
__global__ __launch_bounds__(256) void local_prefix(const float* __restrict__ Wx,
                                                    const int* __restrict__ sortedIdx,
                                                    const float* __restrict__ expT,
                                                    const float* __restrict__ expT2,
                                                    float* __restrict__ localW,
                                                    float* __restrict__ localW2,
                                                    float* __restrict__ chunkTotW,
                                                    float* __restrict__ chunkTotW2,
                                                    float* __restrict__ localZ,
                                                    float* __restrict__ localZ2,
                                                    float* __restrict__ chunkZtot,
                                                    float* __restrict__ chunkZtot2) {
    const int c = blockIdx.x, h = blockIdx.y;
    const int tid = threadIdx.x;
    const int wid = tid >> 6, d = tid & 63;
    const int base = h * NN + c * 64;
    __shared__ float sums[4][64], sums2[4][64];
    float run = 0.f, run2 = 0.f;
    float ex[16], ex2[16];
#pragma unroll
    for (int kk = 0; kk < 16; ++kk) {
        int k = wid * 16 + kk;
        int j = sortedIdx[base + k];
        float w  = expT[base + k];
        float w2 = expT2[base + k];
        float v = Wx[j * HD + h * DD + d];
        ex[kk]  = run;  run  += w  * v;
        ex2[kk] = run2; run2 += w2 * v;
    }
    sums[wid][d] = run; sums2[wid][d] = run2;
    __syncthreads();
    float off = 0.f, off2 = 0.f;
    for (int w = 0; w < 4; ++w) {
        if (w < wid) { off += sums[w][d]; off2 += sums2[w][d]; }
    }
#pragma unroll
    for (int kk = 0; kk < 16; ++kk) {
        int k = wid * 16 + kk;
        localW [(h * NN + c * 64 + k) * 64 + d] = ex[kk]  + off;
        localW2[(h * NN + c * 64 + k) * 64 + d] = ex2[kk] + off2;
    }
    if (wid == 3) {
        chunkTotW [(h * 64 + c) * 64 + d] = off  + run;
        chunkTotW2[(h * 64 + c) * 64 + d] = off2 + run2;
    }
    if (wid == 0) {
        float z0 = expT[base + d];
        float z = z0;
#pragma unroll
        for (int o = 1; o < 64; o <<= 1) { float n = __shfl_up(z, o, 64); if (d >= o) z += n; }
        localZ[h * NN + c * 64 + d] = z - z0;
        if (d == 63) chunkZtot[h * 64 + c] = z;
    } else if (wid == 1) {
        float z0 = expT2[base + d];
        float z = z0;
#pragma unroll
        for (int o = 1; o < 64; o <<= 1) { float n = __shfl_up(z, o, 64); if (d >= o) z += n; }
        localZ2[h * NN + c * 64 + d] = z - z0;
        if (d == 63) chunkZtot2[h * 64 + c] = z;
    }
}

// ---- per-head scan of chunk totals (in place) + grand totals -------------
__global__ __launch_bounds__(256) void chunk_scan(float* __restrict__ chunkTotW,
                                                  float* __restrict__ chunkTotW2,
                                                  float* __restrict__ chunkZtot,
                                                  float* __restrict__ chunkZtot2,
                                                  float* __restrict__ totW,
                                                  float* __restrict__ totW2,
                                                  float* __restrict__ Ztot,
                                                  float* __restrict__ Ztot2) {
    const int h = blockIdx.x;
    const int tid = threadIdx.x;
    const int lane = tid & 63;
    __shared__ float cw[64 * 64];
    __shared__ float cw2[64 * 64];
    __shared__ float zb[64], zb2[64];
#pragma unroll
    for (int it = 0; it < 16; ++it) {
        int lin = it * 256 + tid;
        cw[lin]  = chunkTotW [h * 4096 + lin];
        cw2[lin] = chunkTotW2[h * 4096 + lin];
    }
    if (tid >= 128 && tid < 192) zb[lane]  = chunkZtot [h * 64 + lane];
    if (tid >= 192)              zb2[lane] = chunkZtot2[h * 64 + lane];
    __syncthreads();
    if (tid < 64) {
        float acc = 0.f;
        for (int c = 0; c < 64; ++c) { int idx = c * 64 + tid; float t = cw[idx]; cw[idx] = acc; acc += t; }
        totW[h * 64 + tid] = acc;
    } else if (tid < 128) {
        int d = tid - 64;
        float acc = 0.f;
        for (int c = 0; c < 64; ++c) { int idx = c * 64 + d; float t = cw2[idx]; cw2[idx] = acc; acc += t; }
        totW2[h * 64 + d] = acc;
    } else if (tid < 192) {
        float z0 = zb[lane];
        float z = z0;
#pragma unroll
        for (int o = 1; o < 64; o <<= 1) { float n = __shfl_up(z, o, 64); if (lane >= o) z += n; }
        chunkZtot[h * 64 + lane] = z - z0;
        if (lane == 63) Ztot[h] = z;
    } else {
        float z0 = zb2[lane];
        float z = z0;
#pragma unroll
        for (int o = 1; o < 64; o <<= 1) { float n = __shfl_up(z, o, 64); if (lane >= o) z += n; }
        chunkZtot2[h * 64 + lane] = z - z0;
        if (lane == 63) Ztot2[h] = z;
    }
    __syncthreads();
#pragma unroll
    for (int it = 0; it < 16; ++it) {
        int lin = it * 256 + tid;
        chunkTotW [h * 4096 + lin] = cw[lin];
        chunkTotW2[h * 4096 + lin] = cw2[lin];
    }
}

// ---- output: pure streaming lookups --------------------------------------
__global__ __launch_bounds__(256) void out_kernel(const float* __restrict__ sH,
                                                  const int* __restrict__ cIdx,
                                                  const float* __restrict__ localW,
                                                  const float* __restrict__ localW2,
                                                  const float* __restrict__ chunkTotW,
                                                  const float* __restrict__ chunkTotW2,
                                                  const float* __restrict__ localZ,
                                                  const float* __restrict__ localZ2,
                                                  const float* __restrict__ chunkZtot,
                                                  const float* __restrict__ chunkZtot2,
                                                  const float* __restrict__ totW,
                                                  const float* __restrict__ totW2,
                                                  const float* __restrict__ Ztot,
                                                  const float* __restrict__ Ztot2,
                                                  float* __restrict__ out) {
    const int h = blockIdx.y;
    const int i = blockIdx.x * 4 + (threadIdx.x >> 6);
    const int d = threadIdx.x & 63;
    const float sv = sH[h * NN + i];
    const int c = cIdx[h * NN + i];
    const float es  = expf(sv);
    const float es2 = expf(SLOPE * sv);
    float wpos, wneg, zp, zn;
    if (c == NN) {
        wpos = 0.f; zp = 0.f;
        wneg = totW2[h * 64 + d];
        zn   = Ztot2[h];
    } else {
        float pw  = localW [(h * NN + c) * 64 + d] + chunkTotW [(h * 64 + (c >> 6)) * 64 + d];
        float pw2 = localW2[(h * NN + c) * 64 + d] + chunkTotW2[(h * 64 + (c >> 6)) * 64 + d];
        wpos = totW[h * 64 + d] - pw;
        wneg = pw2;
        float pz  = localZ [h * NN + c] + chunkZtot [h * 64 + (c >> 6)];
        float pz2 = localZ2[h * NN + c] + chunkZtot2[h * 64 + (c >> 6)];
        zp = Ztot[h] - pz;
        zn = pz2;
    }
    out[i * HD + h * DD + d] = (es * wpos + es2 * wneg) / (es * zp + es2 * zn);
}

extern "C" void kernel_launch(void* const* d_in, const int* in_sizes, int n_in,
                              void* d_out, int out_size, void* d_ws, size_t ws_size,
                              hipStream_t stream) {
    const float* x    = (const float*)d_in[0];
    const float* W    = (const float*)d_in[1];
    const float* attn = (const float*)d_in[2];
    float* out = (float*)d_out;

    float* ws = (float*)d_ws;
    size_t o = 0;
    float* Wx        = ws + o; o += (size_t)NN * HD;      // 2,097,152
    float* sH        = ws + o; o += (size_t)NH * NN;
    float* tH        = ws + o; o += (size_t)NH * NN;
    float* expT      = ws + o; o += (size_t)NH * NN;
    float* expT2     = ws + o; o += (size_t)NH * NN;
    int*   sortedIdx = (int*)(ws + o); o += (size_t)NH * NN;
    int*   cIdx      = (int*)(ws + o); o += (size_t)NH * NN;
    float* localZ    = ws + o; o += (size_t)NH * NN;
    float* localZ2   = ws + o; o += (size_t)NH * NN;
    float* chunkTotW  = ws + o; o += (size_t)NH * 64 * 64;
    float* chunkTotW2 = ws + o; o += (size_t)NH * 64 * 64;
    float* chunkZtot  = ws + o; o += (size_t)NH * 64;
    float* chunkZtot2 = ws + o; o += (size_t)NH * 64;
    float* totW   = ws + o; o += (size_t)NH * 64;
    float* totW2  = ws + o; o += (size_t)NH * 64;
    float* Ztot   = ws + o; o += 64;
    float* Ztot2  = ws + o; o += 64;
    float* localW  = ws + o; o += (size_t)NH * NN * 64;   // 2,097,152
    float* localW2 = ws + o; o += (size_t)NH * NN * 64;
    // partial count arrays alias localW/localW2 (consumed before those are written)
    unsigned short* partialR = (unsigned short*)localW;    // NH*NSLICE*NN u16
    unsigned short* partialC = (unsigned short*)localW2;

    gemm_st<<<dim3(NH, NN / 64), dim3(256), 0, stream>>>(x, W, attn, Wx, sH, tH);
    count_partial<<<dim3(NN / 256, NH, NSLICE), dim3(256), 0, stream>>>(tH, sH, partialR, partialC);
    scatter_kernel<<<dim3(NN / 256, NH), dim3(256), 0, stream>>>(tH, partialR, partialC, sortedIdx, expT, expT2, cIdx);
    local_prefix<<<dim3(64, NH), dim3(256), 0, stream>>>(Wx, sortedIdx, expT, expT2, localW, localW2,
                                                         chunkTotW, chunkTotW2, localZ, localZ2, chunkZtot, chunkZtot2);
    chunk_scan<<<dim3(NH), dim3(256), 0, stream>>>(chunkTotW, chunkTotW2, chunkZtot, chunkZtot2,
                                                   totW, totW2, Ztot, Ztot2);
    out_kernel<<<dim3(NN / 4, NH), dim3(256), 0, stream>>>(sH, cIdx, localW, localW2, chunkTotW, chunkTotW2,
                                                           localZ, localZ2, chunkZtot, chunkZtot2,
                                                           totW, totW2, Ztot, Ztot2, out);
}